// Round 4
// baseline (548.600 us; speedup 1.0000x reference)
//
#include <hip/hip_runtime.h>
#include <hip/hip_bf16.h>

typedef __attribute__((ext_vector_type(8))) __bf16 bf16x8;
typedef __attribute__((ext_vector_type(4))) float f32x4;

#define BATCH 16
#define LSEQ 2048
#define DIM 128
#define EPITCH 2056

__device__ __forceinline__ bf16x8 cvt8(float4 a, float4 b) {
    bf16x8 r;
    r[0] = (__bf16)a.x; r[1] = (__bf16)a.y; r[2] = (__bf16)a.z; r[3] = (__bf16)a.w;
    r[4] = (__bf16)b.x; r[5] = (__bf16)b.y; r[6] = (__bf16)b.z; r[7] = (__bf16)b.w;
    return r;
}

// ---------------- preproc: K -> bf16 ----------------
__global__ __launch_bounds__(256)
void cast_k_kernel(const float* __restrict__ in, __bf16* __restrict__ out) {
    size_t i = ((size_t)blockIdx.x * 256 + threadIdx.x) * 8;
    const float4* p = reinterpret_cast<const float4*>(in + i);
    *reinterpret_cast<bf16x8*>(out + i) = cvt8(p[0], p[1]);
}

// ---------------- preproc: V -> bf16 transposed Vt[b][d][k] ----------------
__global__ __launch_bounds__(256)
void transpose_v_kernel(const float* __restrict__ v, __bf16* __restrict__ vt) {
    __shared__ __bf16 t[32][DIM + 8];
    const int b = blockIdx.y, k0 = blockIdx.x * 32;
    const int tid = threadIdx.x;
    {
        const int r = tid >> 3, c8 = tid & 7;
        const float* src = v + ((size_t)b * LSEQ + k0 + r) * DIM;
        #pragma unroll
        for (int j = 0; j < 4; ++j) {
            const int c = (c8 + 8 * j) * 4;
            float4 x = *reinterpret_cast<const float4*>(src + c);
            t[r][c + 0] = (__bf16)x.x; t[r][c + 1] = (__bf16)x.y;
            t[r][c + 2] = (__bf16)x.z; t[r][c + 3] = (__bf16)x.w;
        }
    }
    __syncthreads();
    {
        const int d = tid >> 1, ho = (tid & 1) * 16;
        __bf16* dst = vt + ((size_t)b * DIM + d) * LSEQ + k0 + ho;
        bf16x8 w0, w1;
        #pragma unroll
        for (int j = 0; j < 8; ++j) { w0[j] = t[ho + j][d]; w1[j] = t[ho + 8 + j][d]; }
        *reinterpret_cast<bf16x8*>(dst) = w0;
        *reinterpret_cast<bf16x8*>(dst + 8) = w1;
    }
}

// ---------------- preproc: mask -> fragment-order bits (coalesced + ballot) ----
// mpk[b][qt][wslab][it][lane] bit(t*4+r) = mask[b][qt*16+g*4+r][wslab*512+it*32+t*16+li]
__global__ __launch_bounds__(256)
void pack_mask_kernel(const int* __restrict__ maskg, unsigned char* __restrict__ mp) {
    __shared__ unsigned ball[4][16][16];   // [wave][q][u32-chunk] ; bit = t*16+li
    const int tid  = threadIdx.x;
    const int wave = tid >> 6;
    const int lane = tid & 63;
    const int g    = lane >> 4;
    const int li   = lane & 15;
    const int qt   = blockIdx.x;
    const int b    = blockIdx.y;

    const int* mb = maskg + ((size_t)b * LSEQ + qt * 16) * LSEQ + wave * 512;
    #pragma unroll 4
    for (int q = 0; q < 16; ++q) {
        #pragma unroll
        for (int c = 0; c < 8; ++c) {
            int m = mb[(size_t)q * LSEQ + c * 64 + lane];
            unsigned long long bal = __ballot(m != 0);
            if (lane == 0) {
                ball[wave][q][c * 2]     = (unsigned)bal;
                ball[wave][q][c * 2 + 1] = (unsigned)(bal >> 32);
            }
        }
    }
    // same-wave LDS, in-order; assemble 16 output bytes per lane
    unsigned char* out = mp + ((((size_t)b * 128 + qt) * 4 + wave) * 16) * 64 + lane;
    #pragma unroll
    for (int it = 0; it < 16; ++it) {
        unsigned byte = 0;
        #pragma unroll
        for (int r = 0; r < 4; ++r) {
            unsigned wd = ball[wave][g * 4 + r][it];
            byte |= ((wd >> li) & 1u) << r;
            byte |= ((wd >> (16 + li)) & 1u) << (4 + r);
        }
        out[(size_t)it * 64] = (unsigned char)byte;
    }
}

__device__ __forceinline__ void load_k_pre(const __bf16* __restrict__ kbf, size_t browbase,
                                           int kb, int li, int g, bf16x8* kf) {
    const __bf16* p0 = kbf + (browbase + kb + li) * DIM + g * 8;
    #pragma unroll
    for (int t = 0; t < 2; ++t)
        #pragma unroll
        for (int d = 0; d < 4; ++d)
            kf[t * 4 + d] = *reinterpret_cast<const bf16x8*>(p0 + (size_t)t * 16 * DIM + d * 32);
}

// ============ flashA: O (normalized) + rowinv; no W materialization ============
__global__ __launch_bounds__(256, 3)
void flashA(const float* __restrict__ qg,
            const __bf16* __restrict__ kbf,
            const __bf16* __restrict__ vtb,
            const unsigned char* __restrict__ mpk,
            float* __restrict__ og,
            float* __restrict__ rowinv_ws)
{
    __shared__ __align__(16) __bf16 P[4][16][40];   // per-wave 16x32 P tile (pad 40)
    __shared__ float Osum[16 * DIM];                // 8 KB
    __shared__ float rowpart[4][16];
    __shared__ float rowinv[16];

    const int tid  = threadIdx.x;
    const int wave = tid >> 6;
    const int lane = tid & 63;
    const int g    = lane >> 4;
    const int li   = lane & 15;
    const int qt = blockIdx.x;
    const int b  = blockIdx.y;
    const int q0 = qt * 16;

    for (int i = tid; i < 16 * DIM; i += 256) Osum[i] = 0.0f;

    const float qscale = 0.08838834764831845f * 1.4426950408889634f;
    bf16x8 qf[4];
    {
        const float* qrow = qg + ((size_t)b * LSEQ + q0 + li) * DIM + g * 8;
        #pragma unroll
        for (int d = 0; d < 4; ++d) {
            const float4* p4 = reinterpret_cast<const float4*>(qrow + d * 32);
            float4 x = p4[0];
            float4 y = p4[1];
            x.x *= qscale; x.y *= qscale; x.z *= qscale; x.w *= qscale;
            y.x *= qscale; y.y *= qscale; y.z *= qscale; y.w *= qscale;
            qf[d] = cvt8(x, y);
        }
    }

    float rsum[4] = {0.f, 0.f, 0.f, 0.f};
    f32x4 accO[8];
    #pragma unroll
    for (int i = 0; i < 8; ++i) accO[i] = (f32x4){0.f, 0.f, 0.f, 0.f};

    const int kwave0 = wave * 512;
    const size_t browbase = (size_t)b * LSEQ;
    const __bf16* vbase = vtb + ((size_t)b * DIM + li) * LSEQ + g * 8;
    const unsigned char* mpb = mpk + ((((size_t)b * 128 + qt) * 4 + wave) * 16) * 64 + lane;

    bf16x8 kc[8];
    unsigned mc, mn;
    load_k_pre(kbf, browbase, kwave0, li, g, kc);
    mc = mpb[0];
    mn = mpb[64];

    for (int it = 0; it < 16; ++it) {
        const int kb = kwave0 + it * 32;

        // QK^T (kc prefetched)
        f32x4 s0 = (f32x4){0.f, 0.f, 0.f, 0.f};
        f32x4 s1 = (f32x4){0.f, 0.f, 0.f, 0.f};
        #pragma unroll
        for (int d = 0; d < 4; ++d) {
            s0 = __builtin_amdgcn_mfma_f32_16x16x32_bf16(qf[d], kc[d],     s0, 0, 0, 0);
            s1 = __builtin_amdgcn_mfma_f32_16x16x32_bf16(qf[d], kc[4 + d], s1, 0, 0, 0);
        }

        // issue V loads early (used in PV at the end of the body)
        bf16x8 vc[8];
        #pragma unroll
        for (int dt = 0; dt < 8; ++dt)
            vc[dt] = *reinterpret_cast<const bf16x8*>(vbase + kb + (size_t)dt * 16 * LSEQ);

        // prefetch K for it+1
        const int kbn = (it + 1 < 16) ? kb + 32 : kwave0;
        load_k_pre(kbf, browbase, kbn, li, g, kc);

        // mask + exp2 + P tile + rowsum
        const unsigned mb_ = mc;
        #pragma unroll
        for (int t = 0; t < 2; ++t) {
            f32x4 sv = t ? s1 : s0;
            #pragma unroll
            for (int r = 0; r < 4; ++r) {
                float sc = ((mb_ >> (t * 4 + r)) & 1u) ? -1.0e9f : sv[r];
                float ev = __builtin_amdgcn_exp2f(sc);
                rsum[r] += ev;
                P[wave][g * 4 + r][t * 16 + li] = (__bf16)ev;
            }
        }
        mc = mn;
        mn = mpb[(size_t)((it + 2 < 16) ? it + 2 : 15) * 64];

        // PV (same-wave LDS round-trip for the A-fragment)
        bf16x8 af = *reinterpret_cast<const bf16x8*>(&P[wave][li][g * 8]);
        #pragma unroll
        for (int dt = 0; dt < 8; ++dt)
            accO[dt] = __builtin_amdgcn_mfma_f32_16x16x32_bf16(af, vc[dt], accO[dt], 0, 0, 0);
    }

    // rowsum reduce across li lanes
    #pragma unroll
    for (int off = 1; off < 16; off <<= 1) {
        #pragma unroll
        for (int r = 0; r < 4; ++r) rsum[r] += __shfl_xor(rsum[r], off, 64);
    }
    if (li == 0) {
        #pragma unroll
        for (int r = 0; r < 4; ++r) rowpart[wave][g * 4 + r] = rsum[r];
    }
    __syncthreads();

    #pragma unroll
    for (int dt = 0; dt < 8; ++dt) {
        #pragma unroll
        for (int r = 0; r < 4; ++r)
            atomicAdd(&Osum[(g * 4 + r) * DIM + dt * 16 + li], accO[dt][r]);
    }
    if (tid < 16) {
        float s = rowpart[0][tid] + rowpart[1][tid] + rowpart[2][tid] + rowpart[3][tid];
        float inv = 1.0f / s;
        rowinv[tid] = inv;
        rowinv_ws[browbase + q0 + tid] = inv;
    }
    __syncthreads();

    const size_t obase = (browbase + q0) * DIM;
    for (int i = tid; i < 16 * DIM; i += 256) {
        const int row = i >> 7;
        og[obase + i] = Osum[i] * rowinv[row];
    }
}

// ============ wwriter: recompute scores, write W (stream-out) ============
__global__ __launch_bounds__(256, 4)
void wwriter(const float* __restrict__ qg,
             const __bf16* __restrict__ kbf,
             const unsigned char* __restrict__ mpk,
             const float* __restrict__ rowinv_ws,
             float* __restrict__ wg)
{
    const int tid  = threadIdx.x;
    const int wave = tid >> 6;
    const int lane = tid & 63;
    const int g    = lane >> 4;
    const int li   = lane & 15;
    const int qt = blockIdx.x;
    const int b  = blockIdx.y;
    const int q0 = qt * 16;

    const float qscale = 0.08838834764831845f * 1.4426950408889634f;
    bf16x8 qf[4];
    {
        const float* qrow = qg + ((size_t)b * LSEQ + q0 + li) * DIM + g * 8;
        #pragma unroll
        for (int d = 0; d < 4; ++d) {
            const float4* p4 = reinterpret_cast<const float4*>(qrow + d * 32);
            float4 x = p4[0];
            float4 y = p4[1];
            x.x *= qscale; x.y *= qscale; x.z *= qscale; x.w *= qscale;
            y.x *= qscale; y.y *= qscale; y.z *= qscale; y.w *= qscale;
            qf[d] = cvt8(x, y);
        }
    }

    const size_t browbase = (size_t)b * LSEQ;
    float rinv[4];
    #pragma unroll
    for (int r = 0; r < 4; ++r) rinv[r] = rowinv_ws[browbase + q0 + g * 4 + r];

    const int kwave0 = wave * 512;
    const unsigned char* mpb = mpk + ((((size_t)b * 128 + qt) * 4 + wave) * 16) * 64 + lane;
    float* wrow = wg + (browbase + q0) * LSEQ;

    bf16x8 kc[8];
    unsigned mc, mn;
    load_k_pre(kbf, browbase, kwave0, li, g, kc);
    mc = mpb[0];
    mn = mpb[64];

    for (int it = 0; it < 16; ++it) {
        const int kb = kwave0 + it * 32;

        f32x4 s0 = (f32x4){0.f, 0.f, 0.f, 0.f};
        f32x4 s1 = (f32x4){0.f, 0.f, 0.f, 0.f};
        #pragma unroll
        for (int d = 0; d < 4; ++d) {
            s0 = __builtin_amdgcn_mfma_f32_16x16x32_bf16(qf[d], kc[d],     s0, 0, 0, 0);
            s1 = __builtin_amdgcn_mfma_f32_16x16x32_bf16(qf[d], kc[4 + d], s1, 0, 0, 0);
        }

        const int kbn = (it + 1 < 16) ? kb + 32 : kwave0;
        load_k_pre(kbf, browbase, kbn, li, g, kc);

        const unsigned mb_ = mc;
        #pragma unroll
        for (int t = 0; t < 2; ++t) {
            f32x4 sv = t ? s1 : s0;
            const int col = kb + t * 16 + li;
            #pragma unroll
            for (int r = 0; r < 4; ++r) {
                float sc = ((mb_ >> (t * 4 + r)) & 1u) ? -1.0e9f : sv[r];
                float ev = __builtin_amdgcn_exp2f(sc);
                wrow[(size_t)(g * 4 + r) * LSEQ + col] = ev * rinv[r];
            }
        }
        mc = mn;
        mn = mpb[(size_t)((it + 2 < 16) ? it + 2 : 15) * 64];
    }
}

// ========================= fallback (no workspace) =========================
__global__ __launch_bounds__(256, 2)
void sdpa_fused_plain(const float* __restrict__ qg,
                      const float* __restrict__ kg,
                      const float* __restrict__ vg,
                      const int*   __restrict__ maskg,
                      float* __restrict__ og,
                      float* __restrict__ wg)
{
    __shared__ __align__(16) __bf16 Es[16 * EPITCH];
    __shared__ float Osum[16 * DIM];
    __shared__ float rowpart[4][16];
    __shared__ float rowinv[16];

    const int tid  = threadIdx.x;
    const int wave = tid >> 6;
    const int lane = tid & 63;
    const int g    = lane >> 4;
    const int li   = lane & 15;
    const int qt = blockIdx.x;
    const int b  = blockIdx.y;
    const int q0 = qt * 16;

    for (int i = tid; i < 16 * DIM; i += 256) Osum[i] = 0.0f;

    const float qscale = 0.08838834764831845f * 1.4426950408889634f;
    bf16x8 qf[4];
    {
        const float* qrow = qg + ((size_t)b * LSEQ + q0 + li) * DIM + g * 8;
        #pragma unroll
        for (int d = 0; d < 4; ++d) {
            const float4* p4 = reinterpret_cast<const float4*>(qrow + d * 32);
            float4 x = p4[0];
            float4 y = p4[1];
            x.x *= qscale; x.y *= qscale; x.z *= qscale; x.w *= qscale;
            y.x *= qscale; y.y *= qscale; y.z *= qscale; y.w *= qscale;
            qf[d] = cvt8(x, y);
        }
    }

    float rsum[4] = {0.f, 0.f, 0.f, 0.f};
    f32x4 accO[8];
    #pragma unroll
    for (int i = 0; i < 8; ++i) accO[i] = (f32x4){0.f, 0.f, 0.f, 0.f};

    const int kwave0 = wave * 512;
    const size_t browbase = (size_t)b * LSEQ;

    for (int it = 0; it < 16; ++it) {
        const int kb = kwave0 + it * 32;
        f32x4 s0 = (f32x4){0.f, 0.f, 0.f, 0.f};
        f32x4 s1 = (f32x4){0.f, 0.f, 0.f, 0.f};
        {
            const float* kp0 = kg + (browbase + kb + li) * DIM + g * 8;
            const float* kp1 = kp0 + (size_t)16 * DIM;
            #pragma unroll
            for (int d = 0; d < 4; ++d) {
                const float4* a4 = reinterpret_cast<const float4*>(kp0 + d * 32);
                const float4* b4 = reinterpret_cast<const float4*>(kp1 + d * 32);
                s0 = __builtin_amdgcn_mfma_f32_16x16x32_bf16(qf[d], cvt8(a4[0], a4[1]), s0, 0, 0, 0);
                s1 = __builtin_amdgcn_mfma_f32_16x16x32_bf16(qf[d], cvt8(b4[0], b4[1]), s1, 0, 0, 0);
            }
        }
        const int* mbase = maskg + (browbase + q0) * LSEQ + kb + li;
        #pragma unroll
        for (int t = 0; t < 2; ++t) {
            f32x4 sv = t ? s1 : s0;
            const int col = kb + t * 16 + li;
            #pragma unroll
            for (int r = 0; r < 4; ++r) {
                const int m = mbase[(size_t)(g * 4 + r) * LSEQ + t * 16];
                float sc = m ? -1.0e9f : sv[r];
                float ev = __builtin_amdgcn_exp2f(sc);
                rsum[r] += ev;
                Es[(g * 4 + r) * EPITCH + col] = (__bf16)ev;
            }
        }
        bf16x8 af = *reinterpret_cast<const bf16x8*>(&Es[li * EPITCH + kb + g * 8]);
        const float* vb = vg + (browbase + kb + g * 8) * DIM + li;
        #pragma unroll
        for (int dt = 0; dt < 8; ++dt) {
            const float* vp = vb + dt * 16;
            bf16x8 bf;
            #pragma unroll
            for (int j = 0; j < 8; ++j) bf[j] = (__bf16)vp[(size_t)j * DIM];
            accO[dt] = __builtin_amdgcn_mfma_f32_16x16x32_bf16(af, bf, accO[dt], 0, 0, 0);
        }
    }

    #pragma unroll
    for (int off = 1; off < 16; off <<= 1) {
        #pragma unroll
        for (int r = 0; r < 4; ++r) rsum[r] += __shfl_xor(rsum[r], off, 64);
    }
    if (li == 0) {
        #pragma unroll
        for (int r = 0; r < 4; ++r) rowpart[wave][g * 4 + r] = rsum[r];
    }
    __syncthreads();
    #pragma unroll
    for (int dt = 0; dt < 8; ++dt) {
        #pragma unroll
        for (int r = 0; r < 4; ++r)
            atomicAdd(&Osum[(g * 4 + r) * DIM + dt * 16 + li], accO[dt][r]);
    }
    if (tid < 16) {
        float s = rowpart[0][tid] + rowpart[1][tid] + rowpart[2][tid] + rowpart[3][tid];
        rowinv[tid] = 1.0f / s;
    }
    __syncthreads();

    const size_t wbase = (browbase + q0) * LSEQ;
    for (int i = tid; i < 16 * (LSEQ / 8); i += 256) {
        const int row = i >> 8;
        const int col = (i & 255) * 8;
        bf16x8 e = *reinterpret_cast<const bf16x8*>(&Es[row * EPITCH + col]);
        const float inv = rowinv[row];
        float4 w0, w1;
        w0.x = (float)e[0] * inv; w0.y = (float)e[1] * inv;
        w0.z = (float)e[2] * inv; w0.w = (float)e[3] * inv;
        w1.x = (float)e[4] * inv; w1.y = (float)e[5] * inv;
        w1.z = (float)e[6] * inv; w1.w = (float)e[7] * inv;
        float* dst = wg + wbase + (size_t)row * LSEQ + col;
        *reinterpret_cast<float4*>(dst)     = w0;
        *reinterpret_cast<float4*>(dst + 4) = w1;
    }
    const size_t obase = (browbase + q0) * DIM;
    for (int i = tid; i < 16 * DIM; i += 256) {
        const int row = i >> 7;
        og[obase + i] = Osum[i] * rowinv[row];
    }
}

extern "C" void kernel_launch(void* const* d_in, const int* in_sizes, int n_in,
                              void* d_out, int out_size, void* d_ws, size_t ws_size,
                              hipStream_t stream) {
    const float* q    = (const float*)d_in[0];
    const float* k    = (const float*)d_in[1];
    const float* v    = (const float*)d_in[2];
    const int*   mask = (const int*)d_in[3];
    float* o = (float*)d_out;
    float* w = (float*)d_out + (size_t)BATCH * LSEQ * DIM;

    const size_t nKV    = (size_t)BATCH * LSEQ * DIM;                 // 4.19M elems
    const size_t mpSize = (size_t)BATCH * 128 * 4 * 16 * 64;          // 8 MB
    const size_t riSize = (size_t)BATCH * LSEQ * sizeof(float);       // 128 KB
    const size_t need   = 2 * nKV * sizeof(__bf16) + mpSize + riSize;

    dim3 grid(LSEQ / 16, BATCH);
    if (ws_size >= need) {
        __bf16* kbf = (__bf16*)d_ws;
        __bf16* vt  = kbf + nKV;
        unsigned char* mp = (unsigned char*)(vt + nKV);
        float* ri = (float*)(mp + mpSize);
        cast_k_kernel<<<nKV / 2048, 256, 0, stream>>>(k, kbf);
        transpose_v_kernel<<<dim3(LSEQ / 32, BATCH), 256, 0, stream>>>(v, vt);
        pack_mask_kernel<<<grid, 256, 0, stream>>>(mask, mp);
        flashA<<<grid, 256, 0, stream>>>(q, kbf, vt, mp, o, ri);
        wwriter<<<grid, 256, 0, stream>>>(q, kbf, mp, ri, w);
    } else {
        sdpa_fused_plain<<<grid, 256, 0, stream>>>(q, k, v, mask, o, w);
    }
}

// Round 5
// 474.383 us; speedup vs baseline: 1.1564x; 1.1564x over previous
//
#include <hip/hip_runtime.h>
#include <hip/hip_bf16.h>

typedef __attribute__((ext_vector_type(8))) __bf16 bf16x8;
typedef __attribute__((ext_vector_type(4))) float f32x4;

#define BATCH 16
#define LSEQ 2048
#define DIM 128
#define EPITCH 2056

__device__ __forceinline__ bf16x8 cvt8(float4 a, float4 b) {
    bf16x8 r;
    r[0] = (__bf16)a.x; r[1] = (__bf16)a.y; r[2] = (__bf16)a.z; r[3] = (__bf16)a.w;
    r[4] = (__bf16)b.x; r[5] = (__bf16)b.y; r[6] = (__bf16)b.z; r[7] = (__bf16)b.w;
    return r;
}

// ---------------- preproc: K -> bf16 ----------------
__global__ __launch_bounds__(256)
void cast_k_kernel(const float* __restrict__ in, __bf16* __restrict__ out) {
    size_t i = ((size_t)blockIdx.x * 256 + threadIdx.x) * 8;
    const float4* p = reinterpret_cast<const float4*>(in + i);
    *reinterpret_cast<bf16x8*>(out + i) = cvt8(p[0], p[1]);
}

// ---------------- preproc: V -> bf16 transposed Vt[b][d][k] ----------------
__global__ __launch_bounds__(256)
void transpose_v_kernel(const float* __restrict__ v, __bf16* __restrict__ vt) {
    __shared__ __bf16 t[32][DIM + 8];
    const int b = blockIdx.y, k0 = blockIdx.x * 32;
    const int tid = threadIdx.x;
    {
        const int r = tid >> 3, c8 = tid & 7;
        const float* src = v + ((size_t)b * LSEQ + k0 + r) * DIM;
        #pragma unroll
        for (int j = 0; j < 4; ++j) {
            const int c = (c8 + 8 * j) * 4;
            float4 x = *reinterpret_cast<const float4*>(src + c);
            t[r][c + 0] = (__bf16)x.x; t[r][c + 1] = (__bf16)x.y;
            t[r][c + 2] = (__bf16)x.z; t[r][c + 3] = (__bf16)x.w;
        }
    }
    __syncthreads();
    {
        const int d = tid >> 1, ho = (tid & 1) * 16;
        __bf16* dst = vt + ((size_t)b * DIM + d) * LSEQ + k0 + ho;
        bf16x8 w0, w1;
        #pragma unroll
        for (int j = 0; j < 8; ++j) { w0[j] = t[ho + j][d]; w1[j] = t[ho + 8 + j][d]; }
        *reinterpret_cast<bf16x8*>(dst) = w0;
        *reinterpret_cast<bf16x8*>(dst + 8) = w1;
    }
}

// ---------------- preproc: mask -> fragment-order bits (coalesced + ballot) ----
// mpk[b][qt16][wslab][it][lane] bit(t*4+r) = mask[b][qt16*16+g*4+r][wslab*512+it*32+t*16+li]
__global__ __launch_bounds__(256)
void pack_mask_kernel(const int* __restrict__ maskg, unsigned char* __restrict__ mp) {
    __shared__ unsigned ball[4][16][16];
    const int tid  = threadIdx.x;
    const int wave = tid >> 6;
    const int lane = tid & 63;
    const int g    = lane >> 4;
    const int li   = lane & 15;
    const int qt   = blockIdx.x;
    const int b    = blockIdx.y;

    const int* mb = maskg + ((size_t)b * LSEQ + qt * 16) * LSEQ + wave * 512;
    #pragma unroll 4
    for (int q = 0; q < 16; ++q) {
        #pragma unroll
        for (int c = 0; c < 8; ++c) {
            int m = mb[(size_t)q * LSEQ + c * 64 + lane];
            unsigned long long bal = __ballot(m != 0);
            if (lane == 0) {
                ball[wave][q][c * 2]     = (unsigned)bal;
                ball[wave][q][c * 2 + 1] = (unsigned)(bal >> 32);
            }
        }
    }
    unsigned char* out = mp + ((((size_t)b * 128 + qt) * 4 + wave) * 16) * 64 + lane;
    #pragma unroll
    for (int it = 0; it < 16; ++it) {
        unsigned byte = 0;
        #pragma unroll
        for (int r = 0; r < 4; ++r) {
            unsigned wd = ball[wave][g * 4 + r][it];
            byte |= ((wd >> li) & 1u) << r;
            byte |= ((wd >> (16 + li)) & 1u) << (4 + r);
        }
        out[(size_t)it * 64] = (unsigned char)byte;
    }
}

// ============ attnE: O + rowinv + unnormalized E dump, 32q per block ============
__global__ __launch_bounds__(256, 2)
void attnE(const float* __restrict__ qg,
           const __bf16* __restrict__ kbf,
           const __bf16* __restrict__ vtb,
           const unsigned char* __restrict__ mpk,
           float* __restrict__ og,
           float* __restrict__ rowinv_ws,
           __bf16* __restrict__ Eg)
{
    __shared__ __align__(16) __bf16 P[4][2][16][40];   // per-wave 2x 16x32 P tiles
    __shared__ float Osum[32 * DIM];                   // 16 KB
    __shared__ float rowpart[4][32];
    __shared__ float rowinv[32];

    const int tid  = threadIdx.x;
    const int wave = tid >> 6;
    const int lane = tid & 63;
    const int g    = lane >> 4;
    const int li   = lane & 15;

    // XCD-aware decode: xcd = wgid % 8 (round-robin assumption); batch b pinned to xcd b%8
    const int wgid = blockIdx.x;           // 0..1023
    const int xcd  = wgid & 7;
    const int slot = wgid >> 3;            // 0..127
    const int b    = xcd + 8 * (slot >> 6);
    const int qt   = slot & 63;            // 32-query tile index
    const int q0   = qt * 32;

    for (int i = tid; i < 32 * DIM; i += 256) Osum[i] = 0.0f;

    const float qscale = 0.08838834764831845f * 1.4426950408889634f; // 1/sqrt(128)*log2e
    bf16x8 qf[2][4];
    #pragma unroll
    for (int tile = 0; tile < 2; ++tile) {
        const float* qrow = qg + ((size_t)b * LSEQ + q0 + tile * 16 + li) * DIM + g * 8;
        #pragma unroll
        for (int d = 0; d < 4; ++d) {
            const float4* p4 = reinterpret_cast<const float4*>(qrow + d * 32);
            float4 x = p4[0];
            float4 y = p4[1];
            x.x *= qscale; x.y *= qscale; x.z *= qscale; x.w *= qscale;
            y.x *= qscale; y.y *= qscale; y.z *= qscale; y.w *= qscale;
            qf[tile][d] = cvt8(x, y);
        }
    }

    float rsum[2][4];
    #pragma unroll
    for (int tl = 0; tl < 2; ++tl)
        #pragma unroll
        for (int r = 0; r < 4; ++r) rsum[tl][r] = 0.0f;

    f32x4 accO[2][8];
    #pragma unroll
    for (int tl = 0; tl < 2; ++tl)
        #pragma unroll
        for (int i = 0; i < 8; ++i) accO[tl][i] = (f32x4){0.f, 0.f, 0.f, 0.f};

    const int kw0 = wave * 512;
    const size_t bb = (size_t)b * LSEQ;
    const __bf16* vbase = vtb + ((size_t)b * DIM + li) * LSEQ + g * 8;
    const unsigned char* mp0 = mpk + ((((size_t)b * 128 + qt * 2    ) * 4 + wave) * 16) * 64 + lane;
    const unsigned char* mp1 = mpk + ((((size_t)b * 128 + qt * 2 + 1) * 4 + wave) * 16) * 64 + lane;

    for (int it = 0; it < 16; ++it) {
        const int kb = kw0 + it * 32;

        // ---- issue all independent loads up front (K, V, mask bytes)
        bf16x8 kc[8];
        {
            const __bf16* kp = kbf + (bb + kb + li) * DIM + g * 8;
            #pragma unroll
            for (int t = 0; t < 2; ++t)
                #pragma unroll
                for (int d = 0; d < 4; ++d)
                    kc[t * 4 + d] = *reinterpret_cast<const bf16x8*>(kp + (size_t)t * 16 * DIM + d * 32);
        }
        bf16x8 vc[8];
        #pragma unroll
        for (int dt = 0; dt < 8; ++dt)
            vc[dt] = *reinterpret_cast<const bf16x8*>(vbase + kb + (size_t)dt * 16 * LSEQ);
        const unsigned m0 = mp0[(size_t)it * 64];
        const unsigned m1 = mp1[(size_t)it * 64];

        // ---- QK^T for both q-tiles (K fragments shared)
        f32x4 s[2][2];
        #pragma unroll
        for (int tl = 0; tl < 2; ++tl)
            #pragma unroll
            for (int t = 0; t < 2; ++t) s[tl][t] = (f32x4){0.f, 0.f, 0.f, 0.f};
        #pragma unroll
        for (int d = 0; d < 4; ++d) {
            s[0][0] = __builtin_amdgcn_mfma_f32_16x16x32_bf16(qf[0][d], kc[d],     s[0][0], 0, 0, 0);
            s[0][1] = __builtin_amdgcn_mfma_f32_16x16x32_bf16(qf[0][d], kc[4 + d], s[0][1], 0, 0, 0);
            s[1][0] = __builtin_amdgcn_mfma_f32_16x16x32_bf16(qf[1][d], kc[d],     s[1][0], 0, 0, 0);
            s[1][1] = __builtin_amdgcn_mfma_f32_16x16x32_bf16(qf[1][d], kc[4 + d], s[1][1], 0, 0, 0);
        }

        // ---- mask + exp2 + P stage + rowsum
        #pragma unroll
        for (int tl = 0; tl < 2; ++tl) {
            const unsigned mb_ = tl ? m1 : m0;
            #pragma unroll
            for (int t = 0; t < 2; ++t) {
                #pragma unroll
                for (int r = 0; r < 4; ++r) {
                    float sc = ((mb_ >> (t * 4 + r)) & 1u) ? -1.0e9f : s[tl][t][r];
                    float ev = __builtin_amdgcn_exp2f(sc);
                    rsum[tl][r] += ev;
                    P[wave][tl][g * 4 + r][t * 16 + li] = (__bf16)ev;
                }
            }
        }

        // ---- PV for both q-tiles (V fragments shared)
        {
            bf16x8 af0 = *reinterpret_cast<const bf16x8*>(&P[wave][0][li][g * 8]);
            bf16x8 af1 = *reinterpret_cast<const bf16x8*>(&P[wave][1][li][g * 8]);
            #pragma unroll
            for (int dt = 0; dt < 8; ++dt) {
                accO[0][dt] = __builtin_amdgcn_mfma_f32_16x16x32_bf16(af0, vc[dt], accO[0][dt], 0, 0, 0);
                accO[1][dt] = __builtin_amdgcn_mfma_f32_16x16x32_bf16(af1, vc[dt], accO[1][dt], 0, 0, 0);
            }
        }

        // ---- dump unnormalized E (bf16) from the staged P tiles
        {
            const int row32 = lane >> 1;         // 0..31
            const int q4    = lane & 1;          // col half
            const __bf16* src = &P[wave][row32 >> 4][row32 & 15][q4 * 16];
            bf16x8 e0 = *reinterpret_cast<const bf16x8*>(src);
            bf16x8 e1 = *reinterpret_cast<const bf16x8*>(src + 8);
            __bf16* dst = Eg + (bb + q0 + row32) * LSEQ + kb + q4 * 16;
            *reinterpret_cast<bf16x8*>(dst)     = e0;
            *reinterpret_cast<bf16x8*>(dst + 8) = e1;
        }
    }

    // ---- rowsum reduce across li lanes (within lane group)
    #pragma unroll
    for (int off = 1; off < 16; off <<= 1) {
        #pragma unroll
        for (int tl = 0; tl < 2; ++tl)
            #pragma unroll
            for (int r = 0; r < 4; ++r) rsum[tl][r] += __shfl_xor(rsum[tl][r], off, 64);
    }
    if (li == 0) {
        #pragma unroll
        for (int tl = 0; tl < 2; ++tl)
            #pragma unroll
            for (int r = 0; r < 4; ++r) rowpart[wave][tl * 16 + g * 4 + r] = rsum[tl][r];
    }
    __syncthreads();

    // ---- combine O partials across waves (LDS atomics)
    #pragma unroll
    for (int tl = 0; tl < 2; ++tl)
        #pragma unroll
        for (int dt = 0; dt < 8; ++dt)
            #pragma unroll
            for (int r = 0; r < 4; ++r)
                atomicAdd(&Osum[(tl * 16 + g * 4 + r) * DIM + dt * 16 + li], accO[tl][dt][r]);
    if (tid < 32) {
        float sum = rowpart[0][tid] + rowpart[1][tid] + rowpart[2][tid] + rowpart[3][tid];
        float inv = 1.0f / sum;
        rowinv[tid] = inv;
        rowinv_ws[bb + q0 + tid] = inv;
    }
    __syncthreads();

    // ---- write O = Osum * rowinv (float4, coalesced)
    {
        float* obase = og + (bb + q0) * DIM;
        const float4* os4 = reinterpret_cast<const float4*>(Osum);
        for (int i4 = tid; i4 < 32 * DIM / 4; i4 += 256) {
            const int row = i4 >> 5;
            float4 x = os4[i4];
            const float inv = rowinv[row];
            x.x *= inv; x.y *= inv; x.z *= inv; x.w *= inv;
            *reinterpret_cast<float4*>(obase + i4 * 4) = x;
        }
    }
}

// ============ wstream: W = E * rowinv (pure stream) ============
__global__ __launch_bounds__(256)
void wstream(const __bf16* __restrict__ Eg,
             const float* __restrict__ rowinv_ws,
             float* __restrict__ wg)
{
    const size_t idx8 = ((size_t)blockIdx.x * 256 + threadIdx.x) * 8;
    const size_t row  = idx8 >> 11;
    const float inv = rowinv_ws[row];
    bf16x8 e = *reinterpret_cast<const bf16x8*>(Eg + idx8);
    float4 w0, w1;
    w0.x = (float)e[0] * inv; w0.y = (float)e[1] * inv;
    w0.z = (float)e[2] * inv; w0.w = (float)e[3] * inv;
    w1.x = (float)e[4] * inv; w1.y = (float)e[5] * inv;
    w1.z = (float)e[6] * inv; w1.w = (float)e[7] * inv;
    float* dst = wg + idx8;
    *reinterpret_cast<float4*>(dst)     = w0;
    *reinterpret_cast<float4*>(dst + 4) = w1;
}

// ========================= fallback (no workspace) =========================
__global__ __launch_bounds__(256, 2)
void sdpa_fused_plain(const float* __restrict__ qg,
                      const float* __restrict__ kg,
                      const float* __restrict__ vg,
                      const int*   __restrict__ maskg,
                      float* __restrict__ og,
                      float* __restrict__ wg)
{
    __shared__ __align__(16) __bf16 Es[16 * EPITCH];
    __shared__ float Osum[16 * DIM];
    __shared__ float rowpart[4][16];
    __shared__ float rowinv[16];

    const int tid  = threadIdx.x;
    const int wave = tid >> 6;
    const int lane = tid & 63;
    const int g    = lane >> 4;
    const int li   = lane & 15;
    const int qt = blockIdx.x;
    const int b  = blockIdx.y;
    const int q0 = qt * 16;

    for (int i = tid; i < 16 * DIM; i += 256) Osum[i] = 0.0f;

    const float qscale = 0.08838834764831845f * 1.4426950408889634f;
    bf16x8 qf[4];
    {
        const float* qrow = qg + ((size_t)b * LSEQ + q0 + li) * DIM + g * 8;
        #pragma unroll
        for (int d = 0; d < 4; ++d) {
            const float4* p4 = reinterpret_cast<const float4*>(qrow + d * 32);
            float4 x = p4[0];
            float4 y = p4[1];
            x.x *= qscale; x.y *= qscale; x.z *= qscale; x.w *= qscale;
            y.x *= qscale; y.y *= qscale; y.z *= qscale; y.w *= qscale;
            qf[d] = cvt8(x, y);
        }
    }

    float rsum[4] = {0.f, 0.f, 0.f, 0.f};
    f32x4 accO[8];
    #pragma unroll
    for (int i = 0; i < 8; ++i) accO[i] = (f32x4){0.f, 0.f, 0.f, 0.f};

    const int kwave0 = wave * 512;
    const size_t browbase = (size_t)b * LSEQ;

    for (int it = 0; it < 16; ++it) {
        const int kb = kwave0 + it * 32;
        f32x4 s0 = (f32x4){0.f, 0.f, 0.f, 0.f};
        f32x4 s1 = (f32x4){0.f, 0.f, 0.f, 0.f};
        {
            const float* kp0 = kg + (browbase + kb + li) * DIM + g * 8;
            const float* kp1 = kp0 + (size_t)16 * DIM;
            #pragma unroll
            for (int d = 0; d < 4; ++d) {
                const float4* a4 = reinterpret_cast<const float4*>(kp0 + d * 32);
                const float4* b4 = reinterpret_cast<const float4*>(kp1 + d * 32);
                s0 = __builtin_amdgcn_mfma_f32_16x16x32_bf16(qf[d], cvt8(a4[0], a4[1]), s0, 0, 0, 0);
                s1 = __builtin_amdgcn_mfma_f32_16x16x32_bf16(qf[d], cvt8(b4[0], b4[1]), s1, 0, 0, 0);
            }
        }
        const int* mbase = maskg + (browbase + q0) * LSEQ + kb + li;
        #pragma unroll
        for (int t = 0; t < 2; ++t) {
            f32x4 sv = t ? s1 : s0;
            const int col = kb + t * 16 + li;
            #pragma unroll
            for (int r = 0; r < 4; ++r) {
                const int m = mbase[(size_t)(g * 4 + r) * LSEQ + t * 16];
                float sc = m ? -1.0e9f : sv[r];
                float ev = __builtin_amdgcn_exp2f(sc);
                rsum[r] += ev;
                Es[(g * 4 + r) * EPITCH + col] = (__bf16)ev;
            }
        }
        bf16x8 af = *reinterpret_cast<const bf16x8*>(&Es[li * EPITCH + kb + g * 8]);
        const float* vb = vg + (browbase + kb + g * 8) * DIM + li;
        #pragma unroll
        for (int dt = 0; dt < 8; ++dt) {
            const float* vp = vb + dt * 16;
            bf16x8 bf;
            #pragma unroll
            for (int j = 0; j < 8; ++j) bf[j] = (__bf16)vp[(size_t)j * DIM];
            accO[dt] = __builtin_amdgcn_mfma_f32_16x16x32_bf16(af, bf, accO[dt], 0, 0, 0);
        }
    }

    #pragma unroll
    for (int off = 1; off < 16; off <<= 1) {
        #pragma unroll
        for (int r = 0; r < 4; ++r) rsum[r] += __shfl_xor(rsum[r], off, 64);
    }
    if (li == 0) {
        #pragma unroll
        for (int r = 0; r < 4; ++r) rowpart[wave][g * 4 + r] = rsum[r];
    }
    __syncthreads();
    #pragma unroll
    for (int dt = 0; dt < 8; ++dt) {
        #pragma unroll
        for (int r = 0; r < 4; ++r)
            atomicAdd(&Osum[(g * 4 + r) * DIM + dt * 16 + li], accO[dt][r]);
    }
    if (tid < 16) {
        float s = rowpart[0][tid] + rowpart[1][tid] + rowpart[2][tid] + rowpart[3][tid];
        rowinv[tid] = 1.0f / s;
    }
    __syncthreads();

    const size_t wbase = (browbase + q0) * LSEQ;
    for (int i = tid; i < 16 * (LSEQ / 8); i += 256) {
        const int row = i >> 8;
        const int col = (i & 255) * 8;
        bf16x8 e = *reinterpret_cast<const bf16x8*>(&Es[row * EPITCH + col]);
        const float inv = rowinv[row];
        float4 w0, w1;
        w0.x = (float)e[0] * inv; w0.y = (float)e[1] * inv;
        w0.z = (float)e[2] * inv; w0.w = (float)e[3] * inv;
        w1.x = (float)e[4] * inv; w1.y = (float)e[5] * inv;
        w1.z = (float)e[6] * inv; w1.w = (float)e[7] * inv;
        float* dst = wg + wbase + (size_t)row * LSEQ + col;
        *reinterpret_cast<float4*>(dst)     = w0;
        *reinterpret_cast<float4*>(dst + 4) = w1;
    }
    const size_t obase = (browbase + q0) * DIM;
    for (int i = tid; i < 16 * DIM; i += 256) {
        const int row = i >> 7;
        og[obase + i] = Osum[i] * rowinv[row];
    }
}

extern "C" void kernel_launch(void* const* d_in, const int* in_sizes, int n_in,
                              void* d_out, int out_size, void* d_ws, size_t ws_size,
                              hipStream_t stream) {
    const float* q    = (const float*)d_in[0];
    const float* k    = (const float*)d_in[1];
    const float* v    = (const float*)d_in[2];
    const int*   mask = (const int*)d_in[3];
    float* o = (float*)d_out;
    float* w = (float*)d_out + (size_t)BATCH * LSEQ * DIM;

    const size_t nKV    = (size_t)BATCH * LSEQ * DIM;                 // 4.19M elems
    const size_t mpSize = (size_t)BATCH * 128 * 4 * 16 * 64;          // 8.4 MB
    const size_t riSize = (size_t)BATCH * LSEQ * sizeof(float);       // 131 KB
    const size_t eSize  = (size_t)BATCH * LSEQ * LSEQ * sizeof(__bf16); // 134 MB
    const size_t need   = 2 * nKV * sizeof(__bf16) + mpSize + riSize + eSize;

    if (ws_size >= need) {
        __bf16* kbf = (__bf16*)d_ws;
        __bf16* vt  = kbf + nKV;
        unsigned char* mp = (unsigned char*)(vt + nKV);
        float* ri = (float*)(mp + mpSize);
        __bf16* Eg = (__bf16*)(ri + (size_t)BATCH * LSEQ);
        cast_k_kernel<<<nKV / 2048, 256, 0, stream>>>(k, kbf);
        transpose_v_kernel<<<dim3(LSEQ / 32, BATCH), 256, 0, stream>>>(v, vt);
        pack_mask_kernel<<<dim3(128, BATCH), 256, 0, stream>>>(mask, mp);
        attnE<<<1024, 256, 0, stream>>>(q, kbf, vt, mp, o, ri, Eg);
        wstream<<<(BATCH * LSEQ * LSEQ) / 2048, 256, 0, stream>>>(Eg, ri, w);
    } else {
        dim3 grid(LSEQ / 16, BATCH);
        sdpa_fused_plain<<<grid, 256, 0, stream>>>(q, k, v, mask, o, w);
    }
}

// Round 7
// 306.835 us; speedup vs baseline: 1.7879x; 1.5461x over previous
//
#include <hip/hip_runtime.h>
#include <hip/hip_bf16.h>

typedef __attribute__((ext_vector_type(8))) __bf16 bf16x8;
typedef __attribute__((ext_vector_type(4))) float f32x4;

#define BATCH 16
#define LSEQ 2048
#define DIM 128
#define EPITCH 2056
#define NKBLK 64   // 2048 / 32

__device__ __forceinline__ bf16x8 cvt8(float4 a, float4 b) {
    bf16x8 r;
    r[0] = (__bf16)a.x; r[1] = (__bf16)a.y; r[2] = (__bf16)a.z; r[3] = (__bf16)a.w;
    r[4] = (__bf16)b.x; r[5] = (__bf16)b.y; r[6] = (__bf16)b.z; r[7] = (__bf16)b.w;
    return r;
}

// ============ preproc: K -> fragment-blocked Kf[b][kblk][j][lane] ============
// j = t*4+d ; lane = g*16+li ; unit (bf16x8) = K[b][kblk*32 + t*16 + li][d*32 + g*8 + e]
__global__ __launch_bounds__(256)
void pack_k_kernel(const float* __restrict__ kg, bf16x8* __restrict__ kf) {
    __shared__ __bf16 Ks[32][DIM + 8];
    const int kblk = blockIdx.x, b = blockIdx.y;
    const int tid = threadIdx.x;
    {
        const int r = tid >> 3, c4 = tid & 7;
        const float* src = kg + ((size_t)b * LSEQ + kblk * 32 + r) * DIM;
        #pragma unroll
        for (int jj = 0; jj < 4; ++jj) {
            const int c = (c4 + 8 * jj) * 4;
            float4 x = *reinterpret_cast<const float4*>(src + c);
            Ks[r][c + 0] = (__bf16)x.x; Ks[r][c + 1] = (__bf16)x.y;
            Ks[r][c + 2] = (__bf16)x.z; Ks[r][c + 3] = (__bf16)x.w;
        }
    }
    __syncthreads();
    const int lane = tid & 63, w = tid >> 6;
    const int g = lane >> 4, li = lane & 15;
    bf16x8* dst = kf + ((size_t)b * NKBLK + kblk) * 8 * 64;
    #pragma unroll
    for (int jj = 0; jj < 2; ++jj) {
        const int j = 2 * w + jj;
        const int t = j >> 2, d = j & 3;
        bf16x8 v;
        #pragma unroll
        for (int e = 0; e < 8; ++e) v[e] = Ks[t * 16 + li][d * 32 + g * 8 + e];
        dst[j * 64 + lane] = v;
    }
}

// ============ preproc: V -> fragment-blocked Vf[b][kblk][dt][lane] ============
// unit (bf16x8) = V[b][kblk*32 + g*8 + e][dt*16 + li]
__global__ __launch_bounds__(256)
void pack_v_kernel(const float* __restrict__ vg, bf16x8* __restrict__ vf) {
    __shared__ __bf16 Vs[32][DIM + 8];
    const int kblk = blockIdx.x, b = blockIdx.y;
    const int tid = threadIdx.x;
    {
        const int r = tid >> 3, c4 = tid & 7;
        const float* src = vg + ((size_t)b * LSEQ + kblk * 32 + r) * DIM;
        #pragma unroll
        for (int jj = 0; jj < 4; ++jj) {
            const int c = (c4 + 8 * jj) * 4;
            float4 x = *reinterpret_cast<const float4*>(src + c);
            Vs[r][c + 0] = (__bf16)x.x; Vs[r][c + 1] = (__bf16)x.y;
            Vs[r][c + 2] = (__bf16)x.z; Vs[r][c + 3] = (__bf16)x.w;
        }
    }
    __syncthreads();
    const int lane = tid & 63, w = tid >> 6;
    const int g = lane >> 4, li = lane & 15;
    bf16x8* dst = vf + ((size_t)b * NKBLK + kblk) * 8 * 64;
    #pragma unroll
    for (int jj = 0; jj < 2; ++jj) {
        const int dt = 2 * w + jj;
        bf16x8 v;
        #pragma unroll
        for (int e = 0; e < 8; ++e) v[e] = Vs[g * 8 + e][dt * 16 + li];
        dst[dt * 64 + lane] = v;
    }
}

// ============ preproc: mask -> per-wave bytes mp[b][qt16][kblk][lane] ============
// bit (t*4+r) = mask[b][qt16*16 + g*4 + r][kblk*32 + t*16 + li]
__global__ __launch_bounds__(256)
void pack_mask_kernel(const int* __restrict__ maskg, unsigned char* __restrict__ mp) {
    __shared__ unsigned ball[16][64];   // [q][k/32]
    const int tid  = threadIdx.x;
    const int wave = tid >> 6;
    const int lane = tid & 63;
    const int g    = lane >> 4;
    const int li   = lane & 15;
    const int qt   = blockIdx.x;   // 0..127
    const int b    = blockIdx.y;

    const int* mb = maskg + ((size_t)b * LSEQ + qt * 16) * LSEQ;
    #pragma unroll
    for (int qq = 0; qq < 4; ++qq) {
        const int q = wave * 4 + qq;
        #pragma unroll 8
        for (int c = 0; c < 32; ++c) {
            int m = mb[(size_t)q * LSEQ + c * 64 + lane];
            unsigned long long bal = __ballot(m != 0);
            if (lane == 0) {
                ball[q][c * 2]     = (unsigned)bal;
                ball[q][c * 2 + 1] = (unsigned)(bal >> 32);
            }
        }
    }
    __syncthreads();
    unsigned char* out = mp + ((size_t)b * 128 + qt) * (NKBLK * 64) + lane;
    for (int kb2 = wave; kb2 < NKBLK; kb2 += 4) {
        unsigned byte = 0;
        #pragma unroll
        for (int r = 0; r < 4; ++r) {
            unsigned wd = ball[g * 4 + r][kb2];
            byte |= ((wd >> li) & 1u) << r;
            byte |= ((wd >> (16 + li)) & 1u) << (4 + r);
        }
        out[(size_t)kb2 * 64] = (unsigned char)byte;
    }
}

// ============ attn128: per-wave-complete O + rowinv + E dump ============
__global__ __launch_bounds__(512, 2)
void attn128(const float* __restrict__ qg,
             const bf16x8* __restrict__ kf,
             const bf16x8* __restrict__ vf,
             const unsigned char* __restrict__ mpk,
             float* __restrict__ og,
             float* __restrict__ rowinv_ws,
             __bf16* __restrict__ Eg)
{
    __shared__ __align__(16) __bf16 P[8][16][40];   // per-wave 16x32 P tile

    const int tid  = threadIdx.x;
    const int wave = tid >> 6;     // 0..7
    const int lane = tid & 63;
    const int g    = lane >> 4;
    const int li   = lane & 15;

    // XCD swizzle: batch b pinned to xcd b%8  (256 blocks, 1 per CU)
    const int wgid = blockIdx.x;            // 0..255
    const int xcd  = wgid & 7;
    const int rest = wgid >> 3;             // 0..31
    const int b    = xcd + 8 * (rest & 1);
    const int qb   = rest >> 1;             // 0..15 (128-query block)
    const int q0   = qb * 128 + wave * 16;  // this wave's 16 queries

    const size_t bb = (size_t)b * LSEQ;

    // Q fragments with scale*log2(e)
    const float qscale = 0.08838834764831845f * 1.4426950408889634f;
    bf16x8 qf[4];
    {
        const float* qrow = qg + (bb + q0 + li) * DIM + g * 8;
        #pragma unroll
        for (int d = 0; d < 4; ++d) {
            const float4* p4 = reinterpret_cast<const float4*>(qrow + d * 32);
            float4 x = p4[0];
            float4 y = p4[1];
            x.x *= qscale; x.y *= qscale; x.z *= qscale; x.w *= qscale;
            y.x *= qscale; y.y *= qscale; y.z *= qscale; y.w *= qscale;
            qf[d] = cvt8(x, y);
        }
    }

    float rsum[4] = {0.f, 0.f, 0.f, 0.f};
    f32x4 accO[8];
    #pragma unroll
    for (int i = 0; i < 8; ++i) accO[i] = (f32x4){0.f, 0.f, 0.f, 0.f};

    const bf16x8* Kb = kf + (size_t)b * NKBLK * 8 * 64 + lane;
    const bf16x8* Vb = vf + (size_t)b * NKBLK * 8 * 64 + lane;
    const unsigned char* mpb = mpk + ((size_t)b * 128 + qb * 8 + wave) * (NKBLK * 64) + lane;
    __bf16* Ebase = Eg + (bb + q0 + (lane >> 2)) * LSEQ + (lane & 3) * 8;

    // prologue: K(0), mask(0)
    bf16x8 kc[8], kn[8];
    unsigned mc, mn;
    #pragma unroll
    for (int j = 0; j < 8; ++j) kc[j] = Kb[j * 64];
    mc = mpb[0];

    for (int kblk = 0; kblk < NKBLK; ++kblk) {
        __builtin_amdgcn_s_barrier();   // keep waves phase-aligned (L1 reuse); no waitcnt drain

        const int kn_blk = (kblk + 1 < NKBLK) ? kblk + 1 : 0;

        // 1) V loads for this iteration (consumed at the end)
        bf16x8 vc[8];
        #pragma unroll
        for (int dt = 0; dt < 8; ++dt) vc[dt] = Vb[(size_t)kblk * 512 + dt * 64];

        // 2) K prefetch for next iteration
        #pragma unroll
        for (int j = 0; j < 8; ++j) kn[j] = Kb[(size_t)kn_blk * 512 + j * 64];
        mn = mpb[(size_t)kn_blk * 64];

        // 3) QK^T on current K (in flight since previous iteration)
        f32x4 s0 = (f32x4){0.f, 0.f, 0.f, 0.f};
        f32x4 s1 = (f32x4){0.f, 0.f, 0.f, 0.f};
        #pragma unroll
        for (int d = 0; d < 4; ++d) {
            s0 = __builtin_amdgcn_mfma_f32_16x16x32_bf16(qf[d], kc[d],     s0, 0, 0, 0);
            s1 = __builtin_amdgcn_mfma_f32_16x16x32_bf16(qf[d], kc[4 + d], s1, 0, 0, 0);
        }

        // 4) mask + exp2 + P stage + rowsum
        #pragma unroll
        for (int t = 0; t < 2; ++t) {
            f32x4 sv = t ? s1 : s0;
            #pragma unroll
            for (int r = 0; r < 4; ++r) {
                float sc = ((mc >> (t * 4 + r)) & 1u) ? -1.0e9f : sv[r];
                float ev = __builtin_amdgcn_exp2f(sc);
                rsum[r] += ev;
                P[wave][g * 4 + r][t * 16 + li] = (__bf16)ev;
            }
        }

        // 5) E dump (same-wave LDS order) — nontemporal, don't pollute L2
        {
            bf16x8 ed = *reinterpret_cast<const bf16x8*>(&P[wave][lane >> 2][(lane & 3) * 8]);
            __builtin_nontemporal_store(ed, reinterpret_cast<bf16x8*>(Ebase + kblk * 32));
        }

        // 6) PV (V issued at step 1)
        bf16x8 af = *reinterpret_cast<const bf16x8*>(&P[wave][li][g * 8]);
        #pragma unroll
        for (int dt = 0; dt < 8; ++dt)
            accO[dt] = __builtin_amdgcn_mfma_f32_16x16x32_bf16(af, vc[dt], accO[dt], 0, 0, 0);

        // 7) rotate prefetch
        #pragma unroll
        for (int j = 0; j < 8; ++j) kc[j] = kn[j];
        mc = mn;
    }

    // ---- per-wave rowsum reduce across li lanes (stays within lane group)
    #pragma unroll
    for (int off = 1; off < 16; off <<= 1) {
        #pragma unroll
        for (int r = 0; r < 4; ++r) rsum[r] += __shfl_xor(rsum[r], off, 64);
    }
    float rinv[4];
    #pragma unroll
    for (int r = 0; r < 4; ++r) rinv[r] = 1.0f / rsum[r];

    if (li == 0) {
        #pragma unroll
        for (int r = 0; r < 4; ++r)
            rowinv_ws[bb + q0 + g * 4 + r] = rinv[r];
    }

    // ---- O write: O[q0 + g*4 + r][dt*16 + li] = accO[dt][r] * rinv[r]
    {
        float* ob = og + (bb + q0) * DIM;
        #pragma unroll
        for (int dt = 0; dt < 8; ++dt)
            #pragma unroll
            for (int r = 0; r < 4; ++r)
                __builtin_nontemporal_store(accO[dt][r] * rinv[r],
                    ob + (size_t)(g * 4 + r) * DIM + dt * 16 + li);
    }
}

// ============ wstream: W = E * rowinv (pure stream, nt both sides) ============
__global__ __launch_bounds__(256)
void wstream(const __bf16* __restrict__ Eg,
             const float* __restrict__ rowinv_ws,
             float* __restrict__ wg)
{
    const size_t idx8 = ((size_t)blockIdx.x * 256 + threadIdx.x) * 8;
    const size_t row  = idx8 >> 11;
    const float inv = rowinv_ws[row];
    bf16x8 e = __builtin_nontemporal_load(reinterpret_cast<const bf16x8*>(Eg + idx8));
    f32x4 w0, w1;
    w0[0] = (float)e[0] * inv; w0[1] = (float)e[1] * inv;
    w0[2] = (float)e[2] * inv; w0[3] = (float)e[3] * inv;
    w1[0] = (float)e[4] * inv; w1[1] = (float)e[5] * inv;
    w1[2] = (float)e[6] * inv; w1[3] = (float)e[7] * inv;
    float* dst = wg + idx8;
    __builtin_nontemporal_store(w0, reinterpret_cast<f32x4*>(dst));
    __builtin_nontemporal_store(w1, reinterpret_cast<f32x4*>(dst + 4));
}

// ========================= fallback (no workspace) =========================
__global__ __launch_bounds__(256, 2)
void sdpa_fused_plain(const float* __restrict__ qg,
                      const float* __restrict__ kg,
                      const float* __restrict__ vg,
                      const int*   __restrict__ maskg,
                      float* __restrict__ og,
                      float* __restrict__ wg)
{
    __shared__ __align__(16) __bf16 Es[16 * EPITCH];
    __shared__ float Osum[16 * DIM];
    __shared__ float rowpart[4][16];
    __shared__ float rowinv[16];

    const int tid  = threadIdx.x;
    const int wave = tid >> 6;
    const int lane = tid & 63;
    const int g    = lane >> 4;
    const int li   = lane & 15;
    const int qt = blockIdx.x;
    const int b  = blockIdx.y;
    const int q0 = qt * 16;

    for (int i = tid; i < 16 * DIM; i += 256) Osum[i] = 0.0f;

    const float qscale = 0.08838834764831845f * 1.4426950408889634f;
    bf16x8 qf[4];
    {
        const float* qrow = qg + ((size_t)b * LSEQ + q0 + li) * DIM + g * 8;
        #pragma unroll
        for (int d = 0; d < 4; ++d) {
            const float4* p4 = reinterpret_cast<const float4*>(qrow + d * 32);
            float4 x = p4[0];
            float4 y = p4[1];
            x.x *= qscale; x.y *= qscale; x.z *= qscale; x.w *= qscale;
            y.x *= qscale; y.y *= qscale; y.z *= qscale; y.w *= qscale;
            qf[d] = cvt8(x, y);
        }
    }

    float rsum[4] = {0.f, 0.f, 0.f, 0.f};
    f32x4 accO[8];
    #pragma unroll
    for (int i = 0; i < 8; ++i) accO[i] = (f32x4){0.f, 0.f, 0.f, 0.f};

    const int kwave0 = wave * 512;
    const size_t browbase = (size_t)b * LSEQ;

    for (int it = 0; it < 16; ++it) {
        const int kb = kwave0 + it * 32;
        f32x4 s0 = (f32x4){0.f, 0.f, 0.f, 0.f};
        f32x4 s1 = (f32x4){0.f, 0.f, 0.f, 0.f};
        {
            const float* kp0 = kg + (browbase + kb + li) * DIM + g * 8;
            const float* kp1 = kp0 + (size_t)16 * DIM;
            #pragma unroll
            for (int d = 0; d < 4; ++d) {
                const float4* a4 = reinterpret_cast<const float4*>(kp0 + d * 32);
                const float4* b4 = reinterpret_cast<const float4*>(kp1 + d * 32);
                s0 = __builtin_amdgcn_mfma_f32_16x16x32_bf16(qf[d], cvt8(a4[0], a4[1]), s0, 0, 0, 0);
                s1 = __builtin_amdgcn_mfma_f32_16x16x32_bf16(qf[d], cvt8(b4[0], b4[1]), s1, 0, 0, 0);
            }
        }
        const int* mbase = maskg + (browbase + q0) * LSEQ + kb + li;
        #pragma unroll
        for (int t = 0; t < 2; ++t) {
            f32x4 sv = t ? s1 : s0;
            const int col = kb + t * 16 + li;
            #pragma unroll
            for (int r = 0; r < 4; ++r) {
                const int m = mbase[(size_t)(g * 4 + r) * LSEQ + t * 16];
                float sc = m ? -1.0e9f : sv[r];
                float ev = __builtin_amdgcn_exp2f(sc);
                rsum[r] += ev;
                Es[(g * 4 + r) * EPITCH + col] = (__bf16)ev;
            }
        }
        bf16x8 af = *reinterpret_cast<const bf16x8*>(&Es[li * EPITCH + kb + g * 8]);
        const float* vb = vg + (browbase + kb + g * 8) * DIM + li;
        #pragma unroll
        for (int dt = 0; dt < 8; ++dt) {
            const float* vp = vb + dt * 16;
            bf16x8 bf;
            #pragma unroll
            for (int j = 0; j < 8; ++j) bf[j] = (__bf16)vp[(size_t)j * DIM];
            accO[dt] = __builtin_amdgcn_mfma_f32_16x16x32_bf16(af, bf, accO[dt], 0, 0, 0);
        }
    }

    #pragma unroll
    for (int off = 1; off < 16; off <<= 1) {
        #pragma unroll
        for (int r = 0; r < 4; ++r) rsum[r] += __shfl_xor(rsum[r], off, 64);
    }
    if (li == 0) {
        #pragma unroll
        for (int r = 0; r < 4; ++r) rowpart[wave][g * 4 + r] = rsum[r];
    }
    __syncthreads();
    #pragma unroll
    for (int dt = 0; dt < 8; ++dt) {
        #pragma unroll
        for (int r = 0; r < 4; ++r)
            atomicAdd(&Osum[(g * 4 + r) * DIM + dt * 16 + li], accO[dt][r]);
    }
    if (tid < 16) {
        float s = rowpart[0][tid] + rowpart[1][tid] + rowpart[2][tid] + rowpart[3][tid];
        rowinv[tid] = 1.0f / s;
    }
    __syncthreads();

    const size_t wbase = (browbase + q0) * LSEQ;
    for (int i = tid; i < 16 * (LSEQ / 8); i += 256) {
        const int row = i >> 8;
        const int col = (i & 255) * 8;
        bf16x8 e = *reinterpret_cast<const bf16x8*>(&Es[row * EPITCH + col]);
        const float inv = rowinv[row];
        float4 w0, w1;
        w0.x = (float)e[0] * inv; w0.y = (float)e[1] * inv;
        w0.z = (float)e[2] * inv; w0.w = (float)e[3] * inv;
        w1.x = (float)e[4] * inv; w1.y = (float)e[5] * inv;
        w1.z = (float)e[6] * inv; w1.w = (float)e[7] * inv;
        float* dst = wg + wbase + (size_t)row * LSEQ + col;
        *reinterpret_cast<float4*>(dst)     = w0;
        *reinterpret_cast<float4*>(dst + 4) = w1;
    }
    const size_t obase = (browbase + q0) * DIM;
    for (int i = tid; i < 16 * DIM; i += 256) {
        const int row = i >> 7;
        og[obase + i] = Osum[i] * rowinv[row];
    }
}

extern "C" void kernel_launch(void* const* d_in, const int* in_sizes, int n_in,
                              void* d_out, int out_size, void* d_ws, size_t ws_size,
                              hipStream_t stream) {
    const float* q    = (const float*)d_in[0];
    const float* k    = (const float*)d_in[1];
    const float* v    = (const float*)d_in[2];
    const int*   mask = (const int*)d_in[3];
    float* o = (float*)d_out;
    float* w = (float*)d_out + (size_t)BATCH * LSEQ * DIM;

    const size_t kfSize = (size_t)BATCH * NKBLK * 8 * 64 * sizeof(bf16x8);   // 8.4 MB
    const size_t vfSize = kfSize;                                            // 8.4 MB
    const size_t mpSize = (size_t)BATCH * 128 * NKBLK * 64;                  // 8.4 MB
    const size_t riSize = (size_t)BATCH * LSEQ * sizeof(float);              // 131 KB
    const size_t eSize  = (size_t)BATCH * LSEQ * LSEQ * sizeof(__bf16);      // 134 MB
    const size_t need   = kfSize + vfSize + mpSize + riSize + eSize;

    if (ws_size >= need) {
        bf16x8* kf = (bf16x8*)d_ws;
        bf16x8* vfp = (bf16x8*)((char*)d_ws + kfSize);
        unsigned char* mp = (unsigned char*)((char*)d_ws + kfSize + vfSize);
        float* ri = (float*)((char*)d_ws + kfSize + vfSize + mpSize);
        __bf16* Eg = (__bf16*)((char*)d_ws + kfSize + vfSize + mpSize + riSize);
        pack_k_kernel<<<dim3(NKBLK, BATCH), 256, 0, stream>>>(k, kf);
        pack_v_kernel<<<dim3(NKBLK, BATCH), 256, 0, stream>>>(v, vfp);
        pack_mask_kernel<<<dim3(128, BATCH), 256, 0, stream>>>(mask, mp);
        attn128<<<256, 512, 0, stream>>>(q, kf, vfp, mp, o, ri, Eg);
        wstream<<<(BATCH * (size_t)LSEQ * LSEQ) / 2048, 256, 0, stream>>>(Eg, ri, w);
    } else {
        dim3 grid(LSEQ / 16, BATCH);
        sdpa_fused_plain<<<grid, 256, 0, stream>>>(q, k, v, mask, o, w);
    }
}